// Round 1
// baseline (99.107 us; speedup 1.0000x reference)
//
#include <hip/hip_runtime.h>
#include <math.h>

#define NCLS 80
#define NANCH 3
#define NB 16

__device__ __forceinline__ float softplusf(float x) {
    return fmaxf(x, 0.0f) + log1pf(expf(-fabsf(x)));
}

__global__ void k_init(float* out) { out[0] = 0.0f; }

// Sum softplus(p[...,4]) over all cells of all 3 levels, each scaled by 1/N_level.
__global__ void k_obj(const float* __restrict__ p0, const float* __restrict__ p1,
                      const float* __restrict__ p2, int n0, int n1, int n2,
                      float inv0, float inv1, float inv2, float* out) {
    int idx = blockIdx.x * blockDim.x + threadIdx.x;
    float v = 0.0f;
    if (idx < n0) {
        v = softplusf(p0[(size_t)idx * 85 + 4]) * inv0;
    } else if (idx < n0 + n1) {
        v = softplusf(p1[(size_t)(idx - n0) * 85 + 4]) * inv1;
    } else if (idx < n0 + n1 + n2) {
        v = softplusf(p2[(size_t)(idx - n0 - n1) * 85 + 4]) * inv2;
    }
    for (int o = 32; o > 0; o >>= 1) v += __shfl_down(v, o, 64);
    __shared__ float smem[8];
    int lane = threadIdx.x & 63, wv = threadIdx.x >> 6;
    if (lane == 0) smem[wv] = v;
    __syncthreads();
    if (threadIdx.x == 0) {
        float s = 0.0f;
        int nw = (int)blockDim.x >> 6;
        for (int i = 0; i < nw; ++i) s += smem[i];
        atomicAdd(out, s);
    }
}

// One block per level. Each thread handles one (anchor, target) entry.
__global__ void k_tgt(const float* __restrict__ p0, const float* __restrict__ p1,
                      const float* __restrict__ p2,
                      const float* __restrict__ targets, int T,
                      const float* __restrict__ anchors, float* out) {
    int yi = blockIdx.x;
    const float* p = (yi == 0) ? p0 : (yi == 1) ? p1 : p2;
    int W = (yi == 0) ? 80 : (yi == 1) ? 40 : 20;
    int H = W;
    float stride = (yi == 0) ? 8.0f : (yi == 1) ? 16.0f : 32.0f;
    float Ninv = 1.0f / (float)(NB * NANCH * H * W);

    float vf = 0.0f, lbox = 0.0f, lobj = 0.0f, lcls = 0.0f;
    int e = threadIdx.x;  // entry = a*T + t
    if (e < NANCH * T) {
        int a = e / T, ti = e - a * T;
        const float* tg = targets + (size_t)ti * 6;
        float tx = tg[2] * (float)W, ty = tg[3] * (float)H;
        float tw = tg[4] * (float)W, th = tg[5] * (float)H;
        float aw = anchors[yi * 6 + a * 2 + 0] / stride;
        float ah = anchors[yi * 6 + a * 2 + 1] / stride;
        float rw = tw / aw, rh = th / ah;
        float rmax = fmaxf(fmaxf(rw, 1.0f / rw), fmaxf(rh, 1.0f / rh));
        if (rmax < 4.0f) {
            vf = 1.0f;
            int b = (int)tg[0], c = (int)tg[1];
            int ii = (int)floorf(tx), jj = (int)floorf(ty);
            int gi = min(max(ii, 0), W - 1), gj = min(max(jj, 0), H - 1);
            float tbx = tx - (float)ii, tby = ty - (float)jj;
            const float* ps = p + ((size_t)((b * NANCH + a) * H + gj) * W + gi) * 85;
            float s0 = ps[0], s1 = ps[1], s2 = ps[2], s3 = ps[3], s4 = ps[4];
            float px = 1.0f / (1.0f + expf(-s0));
            float py = 1.0f / (1.0f + expf(-s1));
            float pw = expf(s2) * aw;
            float ph = expf(s3) * ah;
            float b1x1 = px - pw * 0.5f, b1x2 = px + pw * 0.5f;
            float b1y1 = py - ph * 0.5f, b1y2 = py + ph * 0.5f;
            float b2x1 = tbx - tw * 0.5f, b2x2 = tbx + tw * 0.5f;
            float b2y1 = tby - th * 0.5f, b2y2 = tby + th * 0.5f;
            float iw = fmaxf(fminf(b1x2, b2x2) - fmaxf(b1x1, b2x1), 0.0f);
            float ih = fmaxf(fminf(b1y2, b2y2) - fmaxf(b1y1, b2y1), 0.0f);
            float inter = iw * ih;
            float uni = pw * ph + tw * th - inter + 1e-9f;
            float iou = inter / uni;
            lbox = 1.0f - iou;
            lobj = -s4 * fmaxf(iou, 0.0f) * Ninv;  // bce(x,z)-bce(x,0) = -x*z
            float cl = 0.0f;
            for (int j = 0; j < NCLS; ++j) cl += softplusf(ps[5 + j]);
            cl -= ps[5 + c];
            lcls = cl;
        }
    }
    // block reduce 4 quantities
    float cnt = vf;
    for (int o = 32; o > 0; o >>= 1) {
        cnt  += __shfl_down(cnt, o, 64);
        lbox += __shfl_down(lbox, o, 64);
        lobj += __shfl_down(lobj, o, 64);
        lcls += __shfl_down(lcls, o, 64);
    }
    __shared__ float smem[10][4];
    int lane = threadIdx.x & 63, wv = threadIdx.x >> 6;
    if (lane == 0) {
        smem[wv][0] = cnt; smem[wv][1] = lbox; smem[wv][2] = lobj; smem[wv][3] = lcls;
    }
    __syncthreads();
    if (threadIdx.x == 0) {
        float c_s = 0, b_s = 0, o_s = 0, l_s = 0;
        int nw = (int)blockDim.x >> 6;
        for (int i = 0; i < nw; ++i) {
            c_s += smem[i][0]; b_s += smem[i][1]; o_s += smem[i][2]; l_s += smem[i][3];
        }
        float nv = fmaxf(c_s, 1.0f);
        atomicAdd(out, b_s / nv + l_s / (nv * (float)NCLS) + o_s);
    }
}

extern "C" void kernel_launch(void* const* d_in, const int* in_sizes, int n_in,
                              void* d_out, int out_size, void* d_ws, size_t ws_size,
                              hipStream_t stream) {
    const float* p0 = (const float*)d_in[0];
    const float* p1 = (const float*)d_in[1];
    const float* p2 = (const float*)d_in[2];
    const float* targets = (const float*)d_in[3];
    const float* anchors = (const float*)d_in[4];
    float* out = (float*)d_out;

    int n0 = in_sizes[0] / 85;   // 16*3*80*80 = 307200 cells
    int n1 = in_sizes[1] / 85;   // 76800
    int n2 = in_sizes[2] / 85;   // 19200
    int T  = in_sizes[3] / 6;    // 200

    k_init<<<1, 1, 0, stream>>>(out);

    int total = n0 + n1 + n2;
    int threads = 256;
    int blocks = (total + threads - 1) / threads;
    k_obj<<<blocks, threads, 0, stream>>>(p0, p1, p2, n0, n1, n2,
                                          1.0f / (float)n0, 1.0f / (float)n1,
                                          1.0f / (float)n2, out);

    k_tgt<<<3, 640, 0, stream>>>(p0, p1, p2, targets, T, anchors, out);
}

// Round 2
// 21.886 us; speedup vs baseline: 4.5284x; 4.5284x over previous
//
#include <hip/hip_runtime.h>
#include <math.h>

#define NCLS 80
#define NANCH 3
#define NB 16

__device__ __forceinline__ float softplusf(float x) {
    return fmaxf(x, 0.0f) + log1pf(expf(-fabsf(x)));
}

// Objectness background term: sum softplus(p[...,4])/N_level over all cells.
// Each thread handles 4 consecutive cells (independent loads for MLP).
// Block partial -> wsobj[blockIdx.x] (no atomics, no zero-init needed).
__global__ void k_obj(const float* __restrict__ p0, const float* __restrict__ p1,
                      const float* __restrict__ p2, int n0, int n1, int n2,
                      float inv0, float inv1, float inv2,
                      float* __restrict__ wsobj) {
    int total = n0 + n1 + n2;
    int base = (blockIdx.x * blockDim.x + threadIdx.x) * 4;
    float v = 0.0f;
#pragma unroll
    for (int u = 0; u < 4; ++u) {
        int idx = base + u;
        if (idx < total) {
            const float* p; int i2; float inv;
            if (idx < n0)           { p = p0; i2 = idx;           inv = inv0; }
            else if (idx < n0 + n1) { p = p1; i2 = idx - n0;      inv = inv1; }
            else                    { p = p2; i2 = idx - n0 - n1; inv = inv2; }
            v += softplusf(p[(size_t)i2 * 85 + 4]) * inv;
        }
    }
    for (int o = 32; o > 0; o >>= 1) v += __shfl_down(v, o, 64);
    __shared__ float smem[4];
    int lane = threadIdx.x & 63, wv = threadIdx.x >> 6;
    if (lane == 0) smem[wv] = v;
    __syncthreads();
    if (threadIdx.x == 0)
        wsobj[blockIdx.x] = smem[0] + smem[1] + smem[2] + smem[3];
}

// One wave per (level, anchor, target) entry. Lane j handles class j (+ j+64).
// Block writes 12 partials (3 levels x {cnt,lbox,lobjc,lcls}) to its ws row.
__global__ void k_tgt(const float* __restrict__ p0, const float* __restrict__ p1,
                      const float* __restrict__ p2,
                      const float* __restrict__ targets, int T,
                      const float* __restrict__ anchors,
                      float* __restrict__ wstgt) {
    int wv = threadIdx.x >> 6, lane = threadIdx.x & 63;
    int w = blockIdx.x * 4 + wv;
    int perlvl = NANCH * T;
    int nwaves = 3 * perlvl;
    float cnt = 0.0f, lbox = 0.0f, lobjc = 0.0f, lcls = 0.0f;
    int yi = 0;
    if (w < nwaves) {
        yi = w / perlvl;
        int e = w - yi * perlvl;
        int a = e / T, ti = e - a * T;
        const float* p = (yi == 0) ? p0 : (yi == 1) ? p1 : p2;
        int W = (yi == 0) ? 80 : (yi == 1) ? 40 : 20;
        int H = W;
        float stride = (yi == 0) ? 8.0f : (yi == 1) ? 16.0f : 32.0f;
        float Ninv = 1.0f / (float)(NB * NANCH * H * W);
        const float* tg = targets + (size_t)ti * 6;
        float tx = tg[2] * (float)W, ty = tg[3] * (float)H;
        float tw = tg[4] * (float)W, th = tg[5] * (float)H;
        float aw = anchors[yi * 6 + a * 2 + 0] / stride;
        float ah = anchors[yi * 6 + a * 2 + 1] / stride;
        float rw = tw / aw, rh = th / ah;
        float rmax = fmaxf(fmaxf(rw, 1.0f / rw), fmaxf(rh, 1.0f / rh));
        if (rmax < 4.0f) {
            int b = (int)tg[0], c = (int)tg[1];
            int ii = (int)floorf(tx), jj = (int)floorf(ty);
            int gi = min(max(ii, 0), W - 1), gj = min(max(jj, 0), H - 1);
            const float* ps = p + ((size_t)((b * NANCH + a) * H + gj) * W + gi) * 85;
            // lane-parallel class BCE: sum_j softplus(s_j) - s_c
            float cl = softplusf(ps[5 + lane]);
            if (lane < NCLS - 64) cl += softplusf(ps[5 + 64 + lane]);
            if (lane == 0) {
                cnt = 1.0f;
                float tbx = tx - (float)ii, tby = ty - (float)jj;
                float s4 = ps[4];
                float px = 1.0f / (1.0f + expf(-ps[0]));
                float py = 1.0f / (1.0f + expf(-ps[1]));
                float pw = expf(ps[2]) * aw;
                float ph = expf(ps[3]) * ah;
                float b1x1 = px - pw * 0.5f, b1x2 = px + pw * 0.5f;
                float b1y1 = py - ph * 0.5f, b1y2 = py + ph * 0.5f;
                float b2x1 = tbx - tw * 0.5f, b2x2 = tbx + tw * 0.5f;
                float b2y1 = tby - th * 0.5f, b2y2 = tby + th * 0.5f;
                float iw = fmaxf(fminf(b1x2, b2x2) - fmaxf(b1x1, b2x1), 0.0f);
                float ih = fmaxf(fminf(b1y2, b2y2) - fmaxf(b1y1, b2y1), 0.0f);
                float inter = iw * ih;
                float uni = pw * ph + tw * th - inter + 1e-9f;
                float iou = inter / uni;
                lbox = 1.0f - iou;
                lobjc = -s4 * fmaxf(iou, 0.0f) * Ninv;  // bce(x,z)-bce(x,0) = -x*z
                cl -= ps[5 + c];
            }
            lcls = cl;
        }
    }
    for (int o = 32; o > 0; o >>= 1) lcls += __shfl_down(lcls, o, 64);

    __shared__ float wsum[4][4];
    __shared__ int wlvl[4];
    if (lane == 0) {
        wsum[wv][0] = cnt; wsum[wv][1] = lbox; wsum[wv][2] = lobjc; wsum[wv][3] = lcls;
        wlvl[wv] = yi;
    }
    __syncthreads();
    if (threadIdx.x < 12) {
        int lv = threadIdx.x >> 2, k = threadIdx.x & 3;
        float s = 0.0f;
        for (int i = 0; i < 4; ++i)
            if (wlvl[i] == lv) s += wsum[i][k];
        wstgt[(size_t)blockIdx.x * 12 + threadIdx.x] = s;
    }
}

// Single-block reduction of all partials + final combine.
__global__ void k_final(const float* __restrict__ wstgt, int ntb,
                        const float* __restrict__ wsobj, int nob,
                        float* __restrict__ out) {
    int tid = threadIdx.x, lane = tid & 63, wv = tid >> 6;
    float acc[12];
#pragma unroll
    for (int k = 0; k < 12; ++k) acc[k] = 0.0f;
    for (int b = tid; b < ntb; b += blockDim.x) {
#pragma unroll
        for (int k = 0; k < 12; ++k) acc[k] += wstgt[(size_t)b * 12 + k];
    }
    float objacc = 0.0f;
    for (int b = tid; b < nob; b += blockDim.x) objacc += wsobj[b];

    for (int o = 32; o > 0; o >>= 1) {
#pragma unroll
        for (int k = 0; k < 12; ++k) acc[k] += __shfl_down(acc[k], o, 64);
        objacc += __shfl_down(objacc, o, 64);
    }
    __shared__ float smem[4][13];
    if (lane == 0) {
#pragma unroll
        for (int k = 0; k < 12; ++k) smem[wv][k] = acc[k];
        smem[wv][12] = objacc;
    }
    __syncthreads();
    if (tid == 0) {
        float tot[13];
#pragma unroll
        for (int k = 0; k < 13; ++k)
            tot[k] = smem[0][k] + smem[1][k] + smem[2][k] + smem[3][k];
        float res = tot[12];
#pragma unroll
        for (int lv = 0; lv < 3; ++lv) {
            float nv = fmaxf(tot[lv * 4 + 0], 1.0f);
            res += tot[lv * 4 + 1] / nv + tot[lv * 4 + 3] / (nv * (float)NCLS)
                 + tot[lv * 4 + 2];
        }
        out[0] = res;
    }
}

extern "C" void kernel_launch(void* const* d_in, const int* in_sizes, int n_in,
                              void* d_out, int out_size, void* d_ws, size_t ws_size,
                              hipStream_t stream) {
    const float* p0 = (const float*)d_in[0];
    const float* p1 = (const float*)d_in[1];
    const float* p2 = (const float*)d_in[2];
    const float* targets = (const float*)d_in[3];
    const float* anchors = (const float*)d_in[4];
    float* out = (float*)d_out;

    int n0 = in_sizes[0] / 85;
    int n1 = in_sizes[1] / 85;
    int n2 = in_sizes[2] / 85;
    int T  = in_sizes[3] / 6;

    int total = n0 + n1 + n2;
    int nblk_obj = (total + 1023) / 1024;            // 4 cells/thread, 256 thr
    int nwaves = 3 * NANCH * T;
    int nblk_tgt = (nwaves + 3) / 4;                 // 4 waves/block

    float* wstgt = (float*)d_ws;                      // nblk_tgt * 12 floats
    float* wsobj = wstgt + (size_t)nblk_tgt * 12;     // nblk_obj floats

    k_obj<<<nblk_obj, 256, 0, stream>>>(p0, p1, p2, n0, n1, n2,
                                        1.0f / (float)n0, 1.0f / (float)n1,
                                        1.0f / (float)n2, wsobj);
    k_tgt<<<nblk_tgt, 256, 0, stream>>>(p0, p1, p2, targets, T, anchors, wstgt);
    k_final<<<1, 256, 0, stream>>>(wstgt, nblk_tgt, wsobj, nblk_obj, out);
}

// Round 3
// 17.538 us; speedup vs baseline: 5.6509x; 1.2479x over previous
//
#include <hip/hip_runtime.h>
#include <math.h>

#define NCLS 80
#define NANCH 3
#define NB 16

__device__ __forceinline__ float softplusf(float x) {
    return fmaxf(x, 0.0f) + log1pf(expf(-fabsf(x)));
}

// Fused kernel, 512 threads/block.
//  blocks [0, nblk_obj): objectness sweep, 8 cells/thread -> wsobj[blk]
//  blocks [nblk_obj, nblk_obj+nblk_tgt): 8 target-waves/block -> wstgt[blk][12]
__global__ void k_fused(const float* __restrict__ p0, const float* __restrict__ p1,
                        const float* __restrict__ p2, int n0, int n1, int n2,
                        float inv0, float inv1, float inv2,
                        const float* __restrict__ targets, int T,
                        const float* __restrict__ anchors,
                        float* __restrict__ wsobj, int nblk_obj,
                        float* __restrict__ wstgt) {
    int lane = threadIdx.x & 63, wv = threadIdx.x >> 6;

    if (blockIdx.x < (unsigned)nblk_obj) {
        // ---------------- objectness background sweep ----------------
        int total = n0 + n1 + n2;
        int base = (blockIdx.x * blockDim.x + threadIdx.x) * 8;
        float v = 0.0f;
#pragma unroll
        for (int u = 0; u < 8; ++u) {
            int idx = base + u;
            if (idx < total) {
                const float* p; int i2; float inv;
                if (idx < n0)           { p = p0; i2 = idx;           inv = inv0; }
                else if (idx < n0 + n1) { p = p1; i2 = idx - n0;      inv = inv1; }
                else                    { p = p2; i2 = idx - n0 - n1; inv = inv2; }
                v += softplusf(p[(size_t)i2 * 85 + 4]) * inv;
            }
        }
        for (int o = 32; o > 0; o >>= 1) v += __shfl_down(v, o, 64);
        __shared__ float smem[8];
        if (lane == 0) smem[wv] = v;
        __syncthreads();
        if (threadIdx.x == 0) {
            float s = 0.0f;
#pragma unroll
            for (int i = 0; i < 8; ++i) s += smem[i];
            wsobj[blockIdx.x] = s;
        }
        return;
    }

    // ---------------- matched-target waves ----------------
    int bt = blockIdx.x - nblk_obj;
    int w = bt * 8 + wv;                 // global wave id
    int perlvl = NANCH * T;
    int nwaves = 3 * perlvl;
    float cnt = 0.0f, lbox = 0.0f, lobjc = 0.0f, lcls = 0.0f;
    int yi = 0;
    if (w < nwaves) {
        yi = w / perlvl;
        int e = w - yi * perlvl;
        int a = e / T, ti = e - a * T;
        const float* p = (yi == 0) ? p0 : (yi == 1) ? p1 : p2;
        int W = (yi == 0) ? 80 : (yi == 1) ? 40 : 20;
        int H = W;
        float stride = (yi == 0) ? 8.0f : (yi == 1) ? 16.0f : 32.0f;
        float Ninv = 1.0f / (float)(NB * NANCH * H * W);
        const float* tg = targets + (size_t)ti * 6;
        float tx = tg[2] * (float)W, ty = tg[3] * (float)H;
        float tw = tg[4] * (float)W, th = tg[5] * (float)H;
        float aw = anchors[yi * 6 + a * 2 + 0] / stride;
        float ah = anchors[yi * 6 + a * 2 + 1] / stride;
        float rw = tw / aw, rh = th / ah;
        float rmax = fmaxf(fmaxf(rw, 1.0f / rw), fmaxf(rh, 1.0f / rh));
        if (rmax < 4.0f) {
            int b = (int)tg[0], c = (int)tg[1];
            int ii = (int)floorf(tx), jj = (int)floorf(ty);
            int gi = min(max(ii, 0), W - 1), gj = min(max(jj, 0), H - 1);
            const float* ps = p + ((size_t)((b * NANCH + a) * H + gj) * W + gi) * 85;
            float cl = softplusf(ps[5 + lane]);
            if (lane < NCLS - 64) cl += softplusf(ps[5 + 64 + lane]);
            if (lane == 0) {
                cnt = 1.0f;
                float tbx = tx - (float)ii, tby = ty - (float)jj;
                float s4 = ps[4];
                float px = 1.0f / (1.0f + expf(-ps[0]));
                float py = 1.0f / (1.0f + expf(-ps[1]));
                float pw = expf(ps[2]) * aw;
                float ph = expf(ps[3]) * ah;
                float b1x1 = px - pw * 0.5f, b1x2 = px + pw * 0.5f;
                float b1y1 = py - ph * 0.5f, b1y2 = py + ph * 0.5f;
                float b2x1 = tbx - tw * 0.5f, b2x2 = tbx + tw * 0.5f;
                float b2y1 = tby - th * 0.5f, b2y2 = tby + th * 0.5f;
                float iw = fmaxf(fminf(b1x2, b2x2) - fmaxf(b1x1, b2x1), 0.0f);
                float ih = fmaxf(fminf(b1y2, b2y2) - fmaxf(b1y1, b2y1), 0.0f);
                float inter = iw * ih;
                float uni = pw * ph + tw * th - inter + 1e-9f;
                float iou = inter / uni;
                lbox = 1.0f - iou;
                lobjc = -s4 * fmaxf(iou, 0.0f) * Ninv;  // bce(x,z)-bce(x,0)
                cl -= ps[5 + c];
            }
            lcls = cl;
        }
    }
    for (int o = 32; o > 0; o >>= 1) lcls += __shfl_down(lcls, o, 64);

    __shared__ float wsum[8][4];
    __shared__ int wlvl[8];
    if (lane == 0) {
        wsum[wv][0] = cnt; wsum[wv][1] = lbox; wsum[wv][2] = lobjc; wsum[wv][3] = lcls;
        wlvl[wv] = yi;
    }
    __syncthreads();
    if (threadIdx.x < 12) {
        int lv = threadIdx.x >> 2, k = threadIdx.x & 3;
        float s = 0.0f;
#pragma unroll
        for (int i = 0; i < 8; ++i)
            if (wlvl[i] == lv) s += wsum[i][k];
        wstgt[(size_t)bt * 12 + threadIdx.x] = s;
    }
}

// Single-block reduction of all partials + final combine.
__global__ void k_final(const float* __restrict__ wstgt, int ntb,
                        const float* __restrict__ wsobj, int nob,
                        float* __restrict__ out) {
    int tid = threadIdx.x, lane = tid & 63, wv = tid >> 6;
    float acc[12];
#pragma unroll
    for (int k = 0; k < 12; ++k) acc[k] = 0.0f;
    for (int b = tid; b < ntb; b += blockDim.x) {
#pragma unroll
        for (int k = 0; k < 12; ++k) acc[k] += wstgt[(size_t)b * 12 + k];
    }
    float objacc = 0.0f;
    for (int b = tid; b < nob; b += blockDim.x) objacc += wsobj[b];

    for (int o = 32; o > 0; o >>= 1) {
#pragma unroll
        for (int k = 0; k < 12; ++k) acc[k] += __shfl_down(acc[k], o, 64);
        objacc += __shfl_down(objacc, o, 64);
    }
    __shared__ float smem[4][13];
    if (lane == 0) {
#pragma unroll
        for (int k = 0; k < 12; ++k) smem[wv][k] = acc[k];
        smem[wv][12] = objacc;
    }
    __syncthreads();
    if (tid == 0) {
        float tot[13];
#pragma unroll
        for (int k = 0; k < 13; ++k)
            tot[k] = smem[0][k] + smem[1][k] + smem[2][k] + smem[3][k];
        float res = tot[12];
#pragma unroll
        for (int lv = 0; lv < 3; ++lv) {
            float nv = fmaxf(tot[lv * 4 + 0], 1.0f);
            res += tot[lv * 4 + 1] / nv + tot[lv * 4 + 3] / (nv * (float)NCLS)
                 + tot[lv * 4 + 2];
        }
        out[0] = res;
    }
}

extern "C" void kernel_launch(void* const* d_in, const int* in_sizes, int n_in,
                              void* d_out, int out_size, void* d_ws, size_t ws_size,
                              hipStream_t stream) {
    const float* p0 = (const float*)d_in[0];
    const float* p1 = (const float*)d_in[1];
    const float* p2 = (const float*)d_in[2];
    const float* targets = (const float*)d_in[3];
    const float* anchors = (const float*)d_in[4];
    float* out = (float*)d_out;

    int n0 = in_sizes[0] / 85;
    int n1 = in_sizes[1] / 85;
    int n2 = in_sizes[2] / 85;
    int T  = in_sizes[3] / 6;

    int total = n0 + n1 + n2;
    const int THREADS = 512;
    int nblk_obj = (total + THREADS * 8 - 1) / (THREADS * 8);   // 8 cells/thread
    int nwaves = 3 * NANCH * T;
    int nblk_tgt = (nwaves + 7) / 8;                            // 8 waves/block

    float* wstgt = (float*)d_ws;                      // nblk_tgt * 12 floats
    float* wsobj = wstgt + (size_t)nblk_tgt * 12;     // nblk_obj floats

    k_fused<<<nblk_obj + nblk_tgt, THREADS, 0, stream>>>(
        p0, p1, p2, n0, n1, n2,
        1.0f / (float)n0, 1.0f / (float)n1, 1.0f / (float)n2,
        targets, T, anchors, wsobj, nblk_obj, wstgt);

    k_final<<<1, 256, 0, stream>>>(wstgt, nblk_tgt, wsobj, nblk_obj, out);
}